// Round 1
// baseline (210.338 us; speedup 1.0000x reference)
//
#include <hip/hip_runtime.h>
#include <stdint.h>

typedef __attribute__((ext_vector_type(4))) float f32x4;
typedef __attribute__((ext_vector_type(8))) short s16x8;

// ---- geometry constants (fixed problem size) ----
// x: (16, 64, 128, 128) fp32; weight: (64, 64, 6, 6) fp32 (ALREADY in Winograd domain)
// bias: (64,) fp32; out: (16, 64, 128, 128) fp32
// tiles: nt=32 per dim, 1024 per image, 16384 total; PAD=1.
#define NTILES_TOTAL 16384
#define WB_BYTES 294912              // 36*64*64 bf16
// V layout: [tilegroup][ab=36][ti=16][cin=64] bf16 ; full size 16384*36*64*2 = 75497472 B

__device__ __forceinline__ short f2bf(float f) {
    uint32_t u = __builtin_bit_cast(uint32_t, f);
    u = u + 0x7FFFu + ((u >> 16) & 1u);          // round-to-nearest-even
    return (short)(u >> 16);
}

// ---------------- Kernel 0: weight relayout fp32(co,cin,ab) -> bf16 [ab][co*64+cin] ----------------
__global__ __launch_bounds__(256) void wtrans(const float* __restrict__ wf, short* __restrict__ wb) {
    int tid = blockIdx.x * 256 + threadIdx.x;    // 0..4095  == co*64+cin
    const float* src = wf + tid * 36;
    float w[36];
#pragma unroll
    for (int i = 0; i < 9; i++) {
        f32x4 v = *(const f32x4*)(src + 4 * i);
        w[4*i+0] = v[0]; w[4*i+1] = v[1]; w[4*i+2] = v[2]; w[4*i+3] = v[3];
    }
#pragma unroll
    for (int ab = 0; ab < 36; ab++) wb[ab * 4096 + tid] = f2bf(w[ab]);  // coalesced per ab
}

// ---------------- Kernel 1: input transform ----------------
// block = 4-tile strip (same p, q0..q0+3) x 64 cins. 256 threads.
// LDS layout: X[(r*24 + c)*65 + cin], pad 65 -> conflict-free cin-fastest reads.
__global__ __launch_bounds__(256) void itrans(const float* __restrict__ x, short* __restrict__ V,
                                              int base_tile) {
    __shared__ float X[144 * 65];                // 6 rows * 24 cols * 65 = 37440 B
    int t = threadIdx.x;
    int tile0 = base_tile + blockIdx.x * 4;
    int n = tile0 >> 10;
    int rem = tile0 & 1023;
    int p = rem >> 5;
    int q0 = rem & 31;                           // multiple of 4
    const float* xb = x + (size_t)(n * 64) * 16384;
    int row0 = 4 * p - 1;
    int col0 = 4 * q0 - 4;

    // stage: 64 cin * 6 rows * 6 float4 = 2304 slots, coalesced f4 loads
    for (int s = t; s < 2304; s += 256) {
        int cin = s / 36;
        int rs = s - cin * 36;
        int r = rs / 6;
        int c4 = rs - r * 6;
        int gr = row0 + r;
        int gc = col0 + 4 * c4;
        float v0 = 0.f, v1 = 0.f, v2 = 0.f, v3 = 0.f;
        if ((unsigned)gr < 128u) {
            const float* rowp = xb + (size_t)(cin * 128 + gr) * 128;
            if (gc >= 0 && gc + 3 < 128) {
                f32x4 v = *(const f32x4*)(rowp + gc);
                v0 = v[0]; v1 = v[1]; v2 = v[2]; v3 = v[3];
            } else {
                if ((unsigned)(gc + 0) < 128u) v0 = rowp[gc + 0];
                if ((unsigned)(gc + 1) < 128u) v1 = rowp[gc + 1];
                if ((unsigned)(gc + 2) < 128u) v2 = rowp[gc + 2];
                if ((unsigned)(gc + 3) < 128u) v3 = rowp[gc + 3];
            }
        }
        int b = (r * 24 + 4 * c4) * 65 + cin;
        X[b] = v0; X[b + 65] = v1; X[b + 130] = v2; X[b + 195] = v3;
    }
    __syncthreads();

    int cin = t & 63;
    int ti  = t >> 6;                            // 0..3, wave-uniform
    int cofs = 4 * ti + 3;                       // patch col offset in staged coords
    float U[6][6];
#pragma unroll
    for (int c = 0; c < 6; c++) {
        float m0 = X[(0 * 24 + cofs + c) * 65 + cin];
        float m1 = X[(1 * 24 + cofs + c) * 65 + cin];
        float m2 = X[(2 * 24 + cofs + c) * 65 + cin];
        float m3 = X[(3 * 24 + cofs + c) * 65 + cin];
        float m4 = X[(4 * 24 + cofs + c) * 65 + cin];
        float m5 = X[(5 * 24 + cofs + c) * 65 + cin];
        float g = m4 - m2;
        float e = fmaf(-4.f, m2, m4);
        float f = fmaf(-4.f, m1, m3);
        float h = m3 - m1;
        U[0][c] = fmaf(4.f, m0 - m2, g);         // 4m0 -5m2 +m4
        U[1][c] = e + f;                          // -4m1 -4m2 +m3 +m4
        U[2][c] = e - f;                          // 4m1 -4m2 -m3 +m4
        U[3][c] = fmaf(2.f, h, g);                // -2m1 -m2 +2m3 +m4
        U[4][c] = fmaf(-2.f, h, g);               // 2m1 -m2 -2m3 +m4
        U[5][c] = fmaf(4.f, m1 - m3, m5 - m3);    // 4m1 -5m3 +m5
    }
    int lt = tile0 - base_tile + ti;             // local tile in chunk
    int tg = lt >> 4;
    int t16 = lt & 15;
    short* vb = V + (size_t)tg * 36864 + t16 * 64 + cin;   // + ab*1024
#pragma unroll
    for (int a = 0; a < 6; a++) {
        float m0 = U[a][0], m1 = U[a][1], m2 = U[a][2], m3 = U[a][3], m4 = U[a][4], m5 = U[a][5];
        float g = m4 - m2;
        float e = fmaf(-4.f, m2, m4);
        float f = fmaf(-4.f, m1, m3);
        float h = m3 - m1;
        vb[(a * 6 + 0) * 1024] = f2bf(fmaf(4.f, m0 - m2, g));
        vb[(a * 6 + 1) * 1024] = f2bf(e + f);
        vb[(a * 6 + 2) * 1024] = f2bf(e - f);
        vb[(a * 6 + 3) * 1024] = f2bf(fmaf(2.f, h, g));
        vb[(a * 6 + 4) * 1024] = f2bf(fmaf(-2.f, h, g));
        vb[(a * 6 + 5) * 1024] = f2bf(fmaf(4.f, m1 - m3, m5 - m3));
    }
}

// ---------------- Kernel 2: 36x batched GEMM via MFMA + fused output transform ----------------
// block = 4 waves; wave w = cout-group w (16 couts), all waves share one 16-tile group (L1 reuse of V).
// No LDS: A/B fragments are directly coalesced global dwordx4 loads.
__global__ __launch_bounds__(256, 2) void wgemm(const short* __restrict__ V, const short* __restrict__ wb,
                                                const float* __restrict__ bias, float* __restrict__ out,
                                                int base_tile) {
    int t = threadIdx.x;
    int lane = t & 63;
    int cog = t >> 6;                            // 0..3
    int lo = lane & 15;                          // = tile within group (B n-index, A m-index)
    int q = lane >> 4;                           // quad: k-block
    int tg = blockIdx.x;

    const short* wbase = wb + (cog * 16 + lo) * 64 + q * 8;           // + ab*4096 (+32 for k-half 1)
    const short* vbase = V + (size_t)tg * 36864 + lo * 64 + q * 8;    // + ab*1024 (+32)

    f32x4 acc[36];
#pragma unroll
    for (int i = 0; i < 36; i++) acc[i] = (f32x4){0.f, 0.f, 0.f, 0.f};

#pragma unroll
    for (int ab = 0; ab < 36; ab++) {
        s16x8 a0 = *(const s16x8*)(wbase + ab * 4096);
        s16x8 a1 = *(const s16x8*)(wbase + ab * 4096 + 32);
        s16x8 b0 = *(const s16x8*)(vbase + ab * 1024);
        s16x8 b1 = *(const s16x8*)(vbase + ab * 1024 + 32);
        acc[ab] = __builtin_amdgcn_mfma_f32_16x16x32_bf16(a0, b0, acc[ab], 0, 0, 0);
        acc[ab] = __builtin_amdgcn_mfma_f32_16x16x32_bf16(a1, b1, acc[ab], 0, 0, 0);
    }

    // epilogue: D layout col=lane&15 (=tile), row=q*4+r (=local cout) -> all 36 ab lane-local
    int gt = base_tile + tg * 16 + lo;
    int n = gt >> 10;
    int remt = gt & 1023;
    int p = remt >> 5;
    int qq = remt & 31;
#pragma unroll
    for (int r = 0; r < 4; r++) {
        int co = cog * 16 + q * 4 + r;
        float bv = bias[co];
        float z[4][6];
#pragma unroll
        for (int b = 0; b < 6; b++) {
            float m0 = acc[0 * 6 + b][r], m1 = acc[1 * 6 + b][r], m2 = acc[2 * 6 + b][r];
            float m3 = acc[3 * 6 + b][r], m4 = acc[4 * 6 + b][r], m5 = acc[5 * 6 + b][r];
            float s = m1 + m2, d = m1 - m2, s2 = m3 + m4, d2 = m3 - m4;
            z[0][b] = m0 + s + s2;
            z[1][b] = fmaf(2.f, d2, d);
            z[2][b] = fmaf(4.f, s2, s);
            z[3][b] = fmaf(8.f, d2, d) + m5;
        }
        float* ob = out + ((size_t)(n * 64 + co) * 128 + 4 * p) * 128 + 4 * qq;
#pragma unroll
        for (int xr = 0; xr < 4; xr++) {
            float s = z[xr][1] + z[xr][2], d = z[xr][1] - z[xr][2];
            float s2 = z[xr][3] + z[xr][4], d2 = z[xr][3] - z[xr][4];
            f32x4 y;
            y[0] = z[xr][0] + s + s2 + bv;
            y[1] = fmaf(2.f, d2, d) + bv;
            y[2] = fmaf(4.f, s2, s) + bv;
            y[3] = fmaf(8.f, d2, d) + z[xr][5] + bv;
            *(f32x4*)(ob + xr * 128) = y;
        }
    }
}

extern "C" void kernel_launch(void* const* d_in, const int* in_sizes, int n_in,
                              void* d_out, int out_size, void* d_ws, size_t ws_size,
                              hipStream_t stream) {
    const float* x    = (const float*)d_in[0];
    const float* wf   = (const float*)d_in[1];
    const float* bias = (const float*)d_in[2];
    float* out = (float*)d_out;

    short* wb = (short*)d_ws;
    short* V  = (short*)((char*)d_ws + WB_BYTES);

    // pick largest batch-chunking that fits workspace (V for 16384/c tiles)
    const size_t v_full = 75497472ull;
    int chunks = 0;
    const int cand[5] = {1, 2, 4, 8, 16};
    for (int i = 0; i < 5; i++) {
        if ((size_t)WB_BYTES + v_full / (size_t)cand[i] <= ws_size) { chunks = cand[i]; break; }
    }
    if (!chunks) return;  // workspace too small (<~5 MB) — bail cleanly rather than corrupt memory

    wtrans<<<16, 256, 0, stream>>>(wf, wb);
    int tiles_per_chunk = NTILES_TOTAL / chunks;
    for (int i = 0; i < chunks; i++) {
        int base = i * tiles_per_chunk;
        itrans<<<tiles_per_chunk / 4, 256, 0, stream>>>(x, V, base);
        wgemm<<<tiles_per_chunk / 16, 256, 0, stream>>>(V, wb, bias, out, base);
    }
}

// Round 2
// 186.796 us; speedup vs baseline: 1.1260x; 1.1260x over previous
//
#include <hip/hip_runtime.h>
#include <stdint.h>

typedef __attribute__((ext_vector_type(4))) float f32x4;
typedef __attribute__((ext_vector_type(8))) short s16x8;

typedef __attribute__((address_space(1))) const char g8_t;
typedef __attribute__((address_space(3))) char lds8_t;

// ---- geometry constants (fixed problem size) ----
// x: (16, 64, 128, 128) fp32; weight: (64, 64, 6, 6) fp32 (ALREADY in Winograd domain)
// bias: (64,) fp32; out: (16, 64, 128, 128) fp32
// tiles: nt=32 per dim, 1024 per image, 16384 total; PAD=1.
#define NTILES_TOTAL 16384
#define WB_BYTES 294912              // 36*64*64 bf16
// V layout: [tilegroup][ab=36][ti=16][cin=64] bf16 ; full size 16384*36*64*2 = 75497472 B

__device__ __forceinline__ short f2bf(float f) {
    uint32_t u = __builtin_bit_cast(uint32_t, f);
    u = u + 0x7FFFu + ((u >> 16) & 1u);          // round-to-nearest-even
    return (short)(u >> 16);
}

// ---------------- Kernel 0: weight relayout fp32(co,cin,ab) -> bf16 [ab][co*64+cin] ----------------
__global__ __launch_bounds__(256) void wtrans(const float* __restrict__ wf, short* __restrict__ wb) {
    int tid = blockIdx.x * 256 + threadIdx.x;    // 0..4095  == co*64+cin
    const float* src = wf + tid * 36;
    float w[36];
#pragma unroll
    for (int i = 0; i < 9; i++) {
        f32x4 v = *(const f32x4*)(src + 4 * i);
        w[4*i+0] = v[0]; w[4*i+1] = v[1]; w[4*i+2] = v[2]; w[4*i+3] = v[3];
    }
#pragma unroll
    for (int ab = 0; ab < 36; ab++) wb[ab * 4096 + tid] = f2bf(w[ab]);  // coalesced per ab
}

// ---------------- Kernel 1: input transform ----------------
// block = 4-tile strip (same p, q0..q0+3) x 64 cins. 256 threads.
// LDS layout: X[(r*24 + c)*65 + cin], pad 65 -> conflict-free cin-fastest reads.
__global__ __launch_bounds__(256) void itrans(const float* __restrict__ x, short* __restrict__ V,
                                              int base_tile) {
    __shared__ float X[144 * 65];                // 6 rows * 24 cols * 65 = 37440 B
    int t = threadIdx.x;
    int tile0 = base_tile + blockIdx.x * 4;
    int n = tile0 >> 10;
    int rem = tile0 & 1023;
    int p = rem >> 5;
    int q0 = rem & 31;                           // multiple of 4
    const float* xb = x + (size_t)(n * 64) * 16384;
    int row0 = 4 * p - 1;
    int col0 = 4 * q0 - 4;

    // stage: 64 cin * 6 rows * 6 float4 = 2304 slots, coalesced f4 loads
    for (int s = t; s < 2304; s += 256) {
        int cin = s / 36;
        int rs = s - cin * 36;
        int r = rs / 6;
        int c4 = rs - r * 6;
        int gr = row0 + r;
        int gc = col0 + 4 * c4;
        float v0 = 0.f, v1 = 0.f, v2 = 0.f, v3 = 0.f;
        if ((unsigned)gr < 128u) {
            const float* rowp = xb + (size_t)(cin * 128 + gr) * 128;
            if (gc >= 0 && gc + 3 < 128) {
                f32x4 v = *(const f32x4*)(rowp + gc);
                v0 = v[0]; v1 = v[1]; v2 = v[2]; v3 = v[3];
            } else {
                if ((unsigned)(gc + 0) < 128u) v0 = rowp[gc + 0];
                if ((unsigned)(gc + 1) < 128u) v1 = rowp[gc + 1];
                if ((unsigned)(gc + 2) < 128u) v2 = rowp[gc + 2];
                if ((unsigned)(gc + 3) < 128u) v3 = rowp[gc + 3];
            }
        }
        int b = (r * 24 + 4 * c4) * 65 + cin;
        X[b] = v0; X[b + 65] = v1; X[b + 130] = v2; X[b + 195] = v3;
    }
    __syncthreads();

    int cin = t & 63;
    int ti  = t >> 6;                            // 0..3, wave-uniform
    int cofs = 4 * ti + 3;                       // patch col offset in staged coords
    float U[6][6];
#pragma unroll
    for (int c = 0; c < 6; c++) {
        float m0 = X[(0 * 24 + cofs + c) * 65 + cin];
        float m1 = X[(1 * 24 + cofs + c) * 65 + cin];
        float m2 = X[(2 * 24 + cofs + c) * 65 + cin];
        float m3 = X[(3 * 24 + cofs + c) * 65 + cin];
        float m4 = X[(4 * 24 + cofs + c) * 65 + cin];
        float m5 = X[(5 * 24 + cofs + c) * 65 + cin];
        float g = m4 - m2;
        float e = fmaf(-4.f, m2, m4);
        float f = fmaf(-4.f, m1, m3);
        float h = m3 - m1;
        U[0][c] = fmaf(4.f, m0 - m2, g);         // 4m0 -5m2 +m4
        U[1][c] = e + f;                          // -4m1 -4m2 +m3 +m4
        U[2][c] = e - f;                          // 4m1 -4m2 -m3 +m4
        U[3][c] = fmaf(2.f, h, g);                // -2m1 -m2 +2m3 +m4
        U[4][c] = fmaf(-2.f, h, g);               // 2m1 -m2 -2m3 +m4
        U[5][c] = fmaf(4.f, m1 - m3, m5 - m3);    // 4m1 -5m3 +m5
    }
    int lt = tile0 - base_tile + ti;             // local tile in chunk
    int tg = lt >> 4;
    int t16 = lt & 15;
    short* vb = V + (size_t)tg * 36864 + t16 * 64 + cin;   // + ab*1024
#pragma unroll
    for (int a = 0; a < 6; a++) {
        float m0 = U[a][0], m1 = U[a][1], m2 = U[a][2], m3 = U[a][3], m4 = U[a][4], m5 = U[a][5];
        float g = m4 - m2;
        float e = fmaf(-4.f, m2, m4);
        float f = fmaf(-4.f, m1, m3);
        float h = m3 - m1;
        vb[(a * 6 + 0) * 1024] = f2bf(fmaf(4.f, m0 - m2, g));
        vb[(a * 6 + 1) * 1024] = f2bf(e + f);
        vb[(a * 6 + 2) * 1024] = f2bf(e - f);
        vb[(a * 6 + 3) * 1024] = f2bf(fmaf(2.f, h, g));
        vb[(a * 6 + 4) * 1024] = f2bf(fmaf(-2.f, h, g));
        vb[(a * 6 + 5) * 1024] = f2bf(fmaf(4.f, m1 - m3, m5 - m3));
    }
}

// ---------------- Kernel 2: 36x batched GEMM via MFMA + fused output transform ----------------
// block = 4 waves; wave w = cout-group w (16 couts), all waves share one 16-tile group.
// V is staged to LDS with global_load_lds (16B) in two 18-ab rounds (36.9 KB buffer, <64KB limit).
// XOR chunk swizzle (k ^= row&7) applied on the GLOBAL source side during staging (LDS dest must
// be linear: wave-uniform base + lane*16); frag reads apply the same XOR -> 2 lanes/bank = free.
__global__ __launch_bounds__(256, 2) void wgemm(const short* __restrict__ V, const short* __restrict__ wb,
                                                const float* __restrict__ bias, float* __restrict__ out,
                                                int base_tile) {
    __shared__ __align__(16) short Vs[18432];    // 18 ab planes * 16 tiles * 64 cin = 36864 B
    int t = threadIdx.x;
    int lane = t & 63;
    int cog = t >> 6;                            // 0..3
    int lo = lane & 15;                          // = tile within group (B n-index, A m-index)
    int kq = lane >> 4;                          // quad: k-block
    int tg = blockIdx.x;

    const char* vtg = (const char*)V + (size_t)tg * 73728;
    const short* wbase = wb + (cog * 16 + lo) * 64 + kq * 8;   // + ab*4096 (+32 for k-half 1)

    f32x4 acc[36];
#pragma unroll
    for (int i = 0; i < 36; i++) acc[i] = (f32x4){0.f, 0.f, 0.f, 0.f};

    int xs = (lo & 7);                           // per-lane XOR swizzle key for frag reads

#pragma unroll
    for (int rnd = 0; rnd < 2; rnd++) {
        // ---- stage 18 ab planes = 2304 chunks x 16B (9 iters x 256 threads) ----
        const char* src0 = vtg + rnd * 36864;
#pragma unroll
        for (int i = 0; i < 9; i++) {
            int chunk = i * 256 + t;             // 0..2303 ; layout: [ab18][row16][k8]
            int row = (chunk >> 3) & 15;
            int csw = (chunk & ~7) | ((chunk ^ row) & 7);     // swizzle k by row&7
            lds8_t* ldst = (lds8_t*)Vs + (i * 256 + (t & ~63)) * 16;  // wave-uniform base
            __builtin_amdgcn_global_load_lds((g8_t*)(src0 + csw * 16), ldst, 16, 0, 0);
        }
        __syncthreads();

        // ---- 18 ab x 2 MFMAs; B-frags from LDS (swizzled ds_read_b128), A-frags global (L2-hot) ----
#pragma unroll
        for (int abl = 0; abl < 18; abl++) {
            int ab = rnd * 18 + abl;
            s16x8 a0 = *(const s16x8*)(wbase + ab * 4096);
            s16x8 a1 = *(const s16x8*)(wbase + ab * 4096 + 32);
            const short* vrow = Vs + abl * 1024 + lo * 64;
            s16x8 b0 = *(const s16x8*)(vrow + ((kq ^ xs) << 3));
            s16x8 b1 = *(const s16x8*)(vrow + (((4 + kq) ^ xs) << 3));
            acc[ab] = __builtin_amdgcn_mfma_f32_16x16x32_bf16(a0, b0, acc[ab], 0, 0, 0);
            acc[ab] = __builtin_amdgcn_mfma_f32_16x16x32_bf16(a1, b1, acc[ab], 0, 0, 0);
        }
        if (rnd == 0) __syncthreads();           // protect Vs before restaging
    }

    // epilogue: D layout col=lane&15 (=tile), row=kq*4+r (=local cout) -> all 36 ab lane-local
    int gt = base_tile + tg * 16 + lo;
    int n = gt >> 10;
    int remt = gt & 1023;
    int p = remt >> 5;
    int qq = remt & 31;
#pragma unroll
    for (int r = 0; r < 4; r++) {
        int co = cog * 16 + kq * 4 + r;
        float bv = bias[co];
        float z[4][6];
#pragma unroll
        for (int b = 0; b < 6; b++) {
            float m0 = acc[0 * 6 + b][r], m1 = acc[1 * 6 + b][r], m2 = acc[2 * 6 + b][r];
            float m3 = acc[3 * 6 + b][r], m4 = acc[4 * 6 + b][r], m5 = acc[5 * 6 + b][r];
            float s = m1 + m2, d = m1 - m2, s2 = m3 + m4, d2 = m3 - m4;
            z[0][b] = m0 + s + s2;
            z[1][b] = fmaf(2.f, d2, d);
            z[2][b] = fmaf(4.f, s2, s);
            z[3][b] = fmaf(8.f, d2, d) + m5;
        }
        float* ob = out + ((size_t)(n * 64 + co) * 128 + 4 * p) * 128 + 4 * qq;
#pragma unroll
        for (int xr = 0; xr < 4; xr++) {
            float s = z[xr][1] + z[xr][2], d = z[xr][1] - z[xr][2];
            float s2 = z[xr][3] + z[xr][4], d2 = z[xr][3] - z[xr][4];
            f32x4 y;
            y[0] = z[xr][0] + s + s2 + bv;
            y[1] = fmaf(2.f, d2, d) + bv;
            y[2] = fmaf(4.f, s2, s) + bv;
            y[3] = fmaf(8.f, d2, d) + z[xr][5] + bv;
            *(f32x4*)(ob + xr * 128) = y;
        }
    }
}

extern "C" void kernel_launch(void* const* d_in, const int* in_sizes, int n_in,
                              void* d_out, int out_size, void* d_ws, size_t ws_size,
                              hipStream_t stream) {
    const float* x    = (const float*)d_in[0];
    const float* wf   = (const float*)d_in[1];
    const float* bias = (const float*)d_in[2];
    float* out = (float*)d_out;

    short* wb = (short*)d_ws;
    short* V  = (short*)((char*)d_ws + WB_BYTES);

    // pick largest batch-chunking that fits workspace (V for 16384/c tiles)
    const size_t v_full = 75497472ull;
    int chunks = 0;
    const int cand[5] = {1, 2, 4, 8, 16};
    for (int i = 0; i < 5; i++) {
        if ((size_t)WB_BYTES + v_full / (size_t)cand[i] <= ws_size) { chunks = cand[i]; break; }
    }
    if (!chunks) return;  // workspace too small (<~5 MB) — bail cleanly rather than corrupt memory

    wtrans<<<16, 256, 0, stream>>>(wf, wb);
    int tiles_per_chunk = NTILES_TOTAL / chunks;
    for (int i = 0; i < chunks; i++) {
        int base = i * tiles_per_chunk;
        itrans<<<tiles_per_chunk / 4, 256, 0, stream>>>(x, V, base);
        wgemm<<<tiles_per_chunk / 16, 256, 0, stream>>>(V, wb, bias, out, base);
    }
}

// Round 3
// 180.677 us; speedup vs baseline: 1.1642x; 1.0339x over previous
//
#include <hip/hip_runtime.h>
#include <stdint.h>

typedef __attribute__((ext_vector_type(4))) float f32x4;
typedef __attribute__((ext_vector_type(8))) short s16x8;

// ---- geometry (fixed problem) ----
// x: (16,64,128,128) fp32; weight: (64,64,6,6) fp32 (already Winograd-domain); bias fp32
// out: (16,64,128,128) fp32. 4x4 output tiles, nt=32/dim, 16384 tiles total, PAD=1.
#define WB_BYTES 294912              // 36*64*64 bf16 relayout of weights

__device__ __forceinline__ short f2bf(float f) {
    uint32_t u = __builtin_bit_cast(uint32_t, f);
    u = u + 0x7FFFu + ((u >> 16) & 1u);          // round-to-nearest-even
    return (short)(u >> 16);
}

// ---------------- Kernel 0: weight relayout fp32(co,cin,ab) -> bf16 [ab][co*64+cin] ----------------
__global__ __launch_bounds__(256) void wtrans(const float* __restrict__ wf, short* __restrict__ wb) {
    int tid = blockIdx.x * 256 + threadIdx.x;    // 0..4095  == co*64+cin
    const float* src = wf + tid * 36;
    float w[36];
#pragma unroll
    for (int i = 0; i < 9; i++) {
        f32x4 v = *(const f32x4*)(src + 4 * i);
        w[4*i+0] = v[0]; w[4*i+1] = v[1]; w[4*i+2] = v[2]; w[4*i+3] = v[3];
    }
#pragma unroll
    for (int ab = 0; ab < 36; ab++) wb[ab * 4096 + tid] = f2bf(w[ab]);  // coalesced per ab
}

// ---------------- Fused kernel: input transform + 36x GEMM + output transform ----------------
// Block = 4x4 tile super-block (16 tiles) x all 64 cin. 256 threads = 4 waves.
// Per cin-half r (32 cins): stage 18x18 halo/cin into X (odd stride 343 -> conflict-free),
// per ab-half s: threads transform 2 (tile,cin) tasks -> V LDS [ab18][tile16][cin32] bf16,
// then 18 MFMAs (K=32) accumulate into lane-local acc[36]. Epilogue = register-only AT..AT^T.
#define XS 343                                   // 18*18=324 padded to odd 343 (bank-perm)
__global__ __launch_bounds__(256, 2) void wino_fused(const float* __restrict__ x,
                                                     const short* __restrict__ wb,
                                                     const float* __restrict__ bias,
                                                     float* __restrict__ out) {
    __shared__ float X[32 * XS];                 // 43,904 B
    __shared__ __align__(16) short Vs[18 * 16 * 32];  // 18,432 B ; idx = abl*512 + tl*32 + cin
    int t = threadIdx.x;
    int lane = t & 63;
    int cog = t >> 6;                            // 0..3 : cout group (16 couts each)
    int lo = lane & 15;                          // MFMA m/n index: tile (B,n) & cout (A,m)
    int kq = lane >> 4;                          // quad: k-block within MFMA

    int b = blockIdx.x;
    int n = b >> 6;
    int sb = b & 63;
    int p0 = (sb >> 3) * 4;                      // super-block tile origin
    int q0 = (sb & 7) * 4;
    const float* xb = x + (size_t)n * 64 * 16384;
    int row0 = 4 * p0 - 1;
    int col0a = 4 * q0 - 4;                      // f4-aligned staging col origin (X col 0 == global 4q0-1)

    int cin = t & 31;                            // transform task: cin within half
    int tl0 = t >> 5;                            // tiles tl0 and tl0+8

    f32x4 acc[36];
#pragma unroll
    for (int i = 0; i < 36; i++) acc[i] = (f32x4){0.f, 0.f, 0.f, 0.f};

#pragma unroll
    for (int r = 0; r < 2; r++) {
        // ---- stage X: 32 cin x 18 rows x 6 f4-cols (3456 tasks, coalesced f4 loads) ----
#pragma unroll
        for (int i = 0; i < 14; i++) {
            int s = i * 256 + t;
            if (s < 3456) {
                int ci = s / 108;                // 18*6
                int rs = s - ci * 108;
                int row = rs / 6;
                int c4 = rs - row * 6;
                int gr = row0 + row;
                int gc = col0a + 4 * c4;
                float v0 = 0.f, v1 = 0.f, v2 = 0.f, v3 = 0.f;
                if ((unsigned)gr < 128u) {
                    const float* rowp = xb + (size_t)((r * 32 + ci) * 128 + gr) * 128;
                    if (gc >= 0 && gc + 3 < 128) {
                        f32x4 v = *(const f32x4*)(rowp + gc);
                        v0 = v[0]; v1 = v[1]; v2 = v[2]; v3 = v[3];
                    } else {
                        if ((unsigned)(gc + 0) < 128u) v0 = rowp[gc + 0];
                        if ((unsigned)(gc + 1) < 128u) v1 = rowp[gc + 1];
                        if ((unsigned)(gc + 2) < 128u) v2 = rowp[gc + 2];
                        if ((unsigned)(gc + 3) < 128u) v3 = rowp[gc + 3];
                    }
                }
                int base = ci * XS + row * 18;
                int cl = 4 * c4 - 3;             // local col of j=0
                if ((unsigned)(cl + 0) < 18u) X[base + cl + 0] = v0;
                if ((unsigned)(cl + 1) < 18u) X[base + cl + 1] = v1;
                if ((unsigned)(cl + 2) < 18u) X[base + cl + 2] = v2;
                if ((unsigned)(cl + 3) < 18u) X[base + cl + 3] = v3;
            }
        }
        __syncthreads();

#pragma unroll
        for (int s = 0; s < 2; s++) {
            // ---- transforms: 2 tasks/thread, 3 ab-rows (a = 3s..3s+2) each ----
#pragma unroll
            for (int task = 0; task < 2; task++) {
                int tl = tl0 + task * 8;
                int tp = tl >> 2, tq = tl & 3;
                const float* Xb = X + cin * XS + (4 * tp) * 18 + 4 * tq;  // d[rr][c] = Xb[rr*18+c]
                float Ua[3][6];
#pragma unroll
                for (int c = 0; c < 6; c++) {
                    float m0 = Xb[0 * 18 + c], m1 = Xb[1 * 18 + c], m2 = Xb[2 * 18 + c];
                    float m3 = Xb[3 * 18 + c], m4 = Xb[4 * 18 + c], m5 = Xb[5 * 18 + c];
                    if (s == 0) {
                        float e = fmaf(-4.f, m2, m4);
                        float f = fmaf(-4.f, m1, m3);
                        Ua[0][c] = fmaf(4.f, m0 - m2, m4 - m2);   // a=0
                        Ua[1][c] = e + f;                          // a=1
                        Ua[2][c] = e - f;                          // a=2
                    } else {
                        float g = m4 - m2;
                        float h = m3 - m1;
                        Ua[0][c] = fmaf(2.f, h, g);                // a=3
                        Ua[1][c] = fmaf(-2.f, h, g);               // a=4
                        Ua[2][c] = fmaf(4.f, m1 - m3, m5 - m3);    // a=5
                    }
                }
                short* vb = Vs + tl * 32 + cin;                    // + abl*512
#pragma unroll
                for (int ar = 0; ar < 3; ar++) {
                    float m0 = Ua[ar][0], m1 = Ua[ar][1], m2 = Ua[ar][2];
                    float m3 = Ua[ar][3], m4 = Ua[ar][4], m5 = Ua[ar][5];
                    float e = fmaf(-4.f, m2, m4);
                    float f = fmaf(-4.f, m1, m3);
                    float g = m4 - m2;
                    float h = m3 - m1;
                    vb[(ar * 6 + 0) * 512] = f2bf(fmaf(4.f, m0 - m2, g));
                    vb[(ar * 6 + 1) * 512] = f2bf(e + f);
                    vb[(ar * 6 + 2) * 512] = f2bf(e - f);
                    vb[(ar * 6 + 3) * 512] = f2bf(fmaf(2.f, h, g));
                    vb[(ar * 6 + 4) * 512] = f2bf(fmaf(-2.f, h, g));
                    vb[(ar * 6 + 5) * 512] = f2bf(fmaf(4.f, m1 - m3, m5 - m3));
                }
            }
            __syncthreads();

            // ---- GEMM: 18 MFMAs; A from global wb (L2-hot), B from LDS (ds_read_b128) ----
            const short* wb_base = wb + (s * 18) * 4096 + (cog * 16 + lo) * 64 + r * 32 + kq * 8;
            const short* v_base = Vs + lo * 32 + kq * 8;
#pragma unroll
            for (int abl = 0; abl < 18; abl++) {
                s16x8 a0 = *(const s16x8*)(wb_base + abl * 4096);
                s16x8 b0 = *(const s16x8*)(v_base + abl * 512);
                acc[s * 18 + abl] = __builtin_amdgcn_mfma_f32_16x16x32_bf16(a0, b0, acc[s * 18 + abl], 0, 0, 0);
            }
            __syncthreads();                     // V buffer reused next s/r
        }
    }

    // ---- epilogue: D layout col=lo (=tile), row=kq*4+rr (=local cout); all 36 ab lane-local ----
    int p = p0 + (lo >> 2);
    int q = q0 + (lo & 3);
#pragma unroll
    for (int rr = 0; rr < 4; rr++) {
        int co = cog * 16 + kq * 4 + rr;
        float bv = bias[co];
        float z[4][6];
#pragma unroll
        for (int bb = 0; bb < 6; bb++) {
            float m0 = acc[0 * 6 + bb][rr], m1 = acc[1 * 6 + bb][rr], m2 = acc[2 * 6 + bb][rr];
            float m3 = acc[3 * 6 + bb][rr], m4 = acc[4 * 6 + bb][rr], m5 = acc[5 * 6 + bb][rr];
            float s1 = m1 + m2, d1 = m1 - m2, s2 = m3 + m4, d2 = m3 - m4;
            z[0][bb] = m0 + s1 + s2;
            z[1][bb] = fmaf(2.f, d2, d1);
            z[2][bb] = fmaf(4.f, s2, s1);
            z[3][bb] = fmaf(8.f, d2, d1) + m5;
        }
        float* ob = out + ((size_t)(n * 64 + co) * 128 + 4 * p) * 128 + 4 * q;
#pragma unroll
        for (int xr = 0; xr < 4; xr++) {
            float s1 = z[xr][1] + z[xr][2], d1 = z[xr][1] - z[xr][2];
            float s2 = z[xr][3] + z[xr][4], d2 = z[xr][3] - z[xr][4];
            f32x4 y;
            y[0] = z[xr][0] + s1 + s2 + bv;
            y[1] = fmaf(2.f, d2, d1) + bv;
            y[2] = fmaf(4.f, s2, s1) + bv;
            y[3] = fmaf(8.f, d2, d1) + z[xr][5] + bv;
            *(f32x4*)(ob + xr * 128) = y;
        }
    }
}

extern "C" void kernel_launch(void* const* d_in, const int* in_sizes, int n_in,
                              void* d_out, int out_size, void* d_ws, size_t ws_size,
                              hipStream_t stream) {
    const float* x    = (const float*)d_in[0];
    const float* wf   = (const float*)d_in[1];
    const float* bias = (const float*)d_in[2];
    float* out = (float*)d_out;

    if (ws_size < WB_BYTES) return;              // need 295 KB scratch for bf16 weights
    short* wb = (short*)d_ws;

    wtrans<<<16, 256, 0, stream>>>(wf, wb);
    wino_fused<<<1024, 256, 0, stream>>>(x, wb, bias, out);
}